// Round 3
// baseline (177.436 us; speedup 1.0000x reference)
//
#include <hip/hip_runtime.h>

#define BTOT   524288
#define TILES  4096            // BTOT / 128
#define TN     8               // Taylor order for expm

typedef __attribute__((ext_vector_type(8))) short s8v;   // 8 x bf16 bits
typedef __attribute__((ext_vector_type(4))) float f4v;

#define MFMA(a,b,c) __builtin_amdgcn_mfma_f32_16x16x32_bf16((a),(b),(c),0,0,0)

__device__ __forceinline__ short f2b(float f) {          // f32 -> bf16 (RNE)
  union { float f; unsigned u; } v; v.f = f;
  unsigned r = v.u + 0x7fffu + ((v.u >> 16) & 1u);
  return (short)(r >> 16);
}
__device__ __forceinline__ float b2f(short s) {
  union { float f; unsigned u; } v; v.u = ((unsigned)(unsigned short)s) << 16;
  return v.f;
}

// MFMA fragment load: lane holds M[row0 + (l&15)][kbase + (l>>4)*8 + i], i=0..7
__device__ __forceinline__ s8v ldfrag(const short* base, int row0, int kbase, int stride) {
  const int l = threadIdx.x & 63;
  return *(const s8v*)(base + (row0 + (l & 15)) * stride + kbase + (l >> 4) * 8);
}

// pack 8 f32 (two f4v) -> s8v bf16
__device__ __forceinline__ s8v pack8(f4v u, f4v v) {
  s8v w;
  w[0] = f2b(u[0]); w[1] = f2b(u[1]); w[2] = f2b(u[2]); w[3] = f2b(u[3]);
  w[4] = f2b(v[0]); w[5] = f2b(v[1]); w[6] = f2b(v[2]); w[7] = f2b(v[3]);
  return w;
}

// ---------------------------------------------------------------------------
// Kernel 1: K = expm(A*t/24); emit M1 = K[:, :64] (bf16) and W2K = K @ phi_W2
// (bf16). Single block, 512 threads. Split-bf16 (hi+lo) MFMA matmuls.
// ---------------------------------------------------------------------------
__global__ __launch_bounds__(512, 2) void koop_prep(
    const float* __restrict__ tptr, const float* __restrict__ Ag,
    const float* __restrict__ W2g, short* __restrict__ m1out,
    short* __restrict__ w2kout) {
  extern __shared__ __align__(16) char smem[];
  short* RThi = (short*)smem;              // [128][136]  (RT[col][row] of R)
  short* RTlo = RThi + 128 * 136;          // [128][136]
  float* sW2  = (float*)(RTlo + 128 * 136);// [128][96] f32
  float* sred = sW2 + 128 * 96;            // [130]
  float* scratch = (float*)smem;           // [128][128] f32 alias (dead before RT writes)

  const int tid = threadIdx.x;
  const int lane = tid & 63, wid = tid >> 6;
  const int c_ = lane & 15, g_ = lane >> 4;
  const int mr = wid * 16;

  const float s = tptr[0] * (1.0f / 24.0f);
  for (int i = tid; i < 128 * 128; i += 512) scratch[i] = Ag[i] * s;
  for (int i = tid; i < 128 * 96;  i += 512) sW2[i] = W2g[i];
  __syncthreads();

  if (tid < 128) {
    float su = 0.f;
    for (int j = 0; j < 128; ++j) su += fabsf(scratch[tid * 128 + j]);
    sred[tid] = su;
  }
  __syncthreads();
  if (tid == 0) {
    float m = 0.f;
    for (int i = 0; i < 128; ++i) m = fmaxf(m, sred[i]);
    int j = 0; float sc = 1.f;
    while (m > 0.5f && j < 20) { m *= 0.5f; sc *= 0.5f; ++j; }
    sred[128] = (float)j; sred[129] = sc;
  }
  __syncthreads();
  const int jsq = (int)sred[128];
  const float sc = sred[129];

  s8v Ahi[4], Alo[4];
#pragma unroll
  for (int ks = 0; ks < 4; ++ks) {
    const float* p = scratch + (mr + c_) * 128 + ks * 32 + g_ * 8;
    f4v u = *(const f4v*)p, v = *(const f4v*)(p + 4);
    float vals[8] = {u[0], u[1], u[2], u[3], v[0], v[1], v[2], v[3]};
#pragma unroll
    for (int i = 0; i < 8; ++i) {
      float y = vals[i] * sc;
      short h = f2b(y);
      Ahi[ks][i] = h;
      Alo[ks][i] = f2b(y - b2f(h));
    }
  }
  float yv[32];
#pragma unroll
  for (int e = 0; e < 32; ++e) yv[e] = scratch[tid * 32 + e];
  __syncthreads();

#pragma unroll
  for (int e = 0; e < 32; ++e) {
    int idx = tid * 32 + e;
    int r = idx >> 7, c = idx & 127;
    float v = yv[e] * sc * (1.0f / TN) + ((r == c) ? 1.0f : 0.0f);
    short h = f2b(v);
    RThi[c * 136 + r] = h;
    RTlo[c * 136 + r] = f2b(v - b2f(h));
  }
  __syncthreads();

  for (int k = TN - 1; k >= 1; --k) {
    f4v acc[8];
#pragma unroll
    for (int nt = 0; nt < 8; ++nt) acc[nt] = (f4v){0.f, 0.f, 0.f, 0.f};
#pragma unroll
    for (int ks = 0; ks < 4; ++ks) {
#pragma unroll
      for (int nt = 0; nt < 8; ++nt) {
        s8v bh = ldfrag(RThi, nt * 16, ks * 32, 136);
        s8v bl = ldfrag(RTlo, nt * 16, ks * 32, 136);
        acc[nt] = MFMA(Ahi[ks], bh, acc[nt]);
        acc[nt] = MFMA(Alo[ks], bh, acc[nt]);
        acc[nt] = MFMA(Ahi[ks], bl, acc[nt]);
      }
    }
    __syncthreads();
    const float invk = 1.0f / (float)k;
#pragma unroll
    for (int nt = 0; nt < 8; ++nt)
#pragma unroll
      for (int r = 0; r < 4; ++r) {
        int row = mr + g_ * 4 + r, col = nt * 16 + c_;
        float v = acc[nt][r] * invk + ((row == col) ? 1.0f : 0.0f);
        short h = f2b(v);
        RThi[col * 136 + row] = h;
        RTlo[col * 136 + row] = f2b(v - b2f(h));
      }
    __syncthreads();
  }

  for (int it = 0; it < jsq; ++it) {
    s8v Shi[4], Slo[4];
#pragma unroll
    for (int ks = 0; ks < 4; ++ks) {
      int m = mr + c_;
      int k0 = ks * 32 + g_ * 8;
#pragma unroll
      for (int i = 0; i < 8; ++i) {
        Shi[ks][i] = RThi[(k0 + i) * 136 + m];
        Slo[ks][i] = RTlo[(k0 + i) * 136 + m];
      }
    }
    f4v acc[8];
#pragma unroll
    for (int nt = 0; nt < 8; ++nt) acc[nt] = (f4v){0.f, 0.f, 0.f, 0.f};
#pragma unroll
    for (int ks = 0; ks < 4; ++ks) {
#pragma unroll
      for (int nt = 0; nt < 8; ++nt) {
        s8v bh = ldfrag(RThi, nt * 16, ks * 32, 136);
        s8v bl = ldfrag(RTlo, nt * 16, ks * 32, 136);
        acc[nt] = MFMA(Shi[ks], bh, acc[nt]);
        acc[nt] = MFMA(Slo[ks], bh, acc[nt]);
        acc[nt] = MFMA(Shi[ks], bl, acc[nt]);
      }
    }
    __syncthreads();
#pragma unroll
    for (int nt = 0; nt < 8; ++nt)
#pragma unroll
      for (int r = 0; r < 4; ++r) {
        int row = mr + g_ * 4 + r, col = nt * 16 + c_;
        float v = acc[nt][r];
        short h = f2b(v);
        RThi[col * 136 + row] = h;
        RTlo[col * 136 + row] = f2b(v - b2f(h));
      }
    __syncthreads();
  }

  for (int i = tid; i < 128 * 64; i += 512) {
    int n = i >> 6, kk = i & 63;
    m1out[i] = f2b(b2f(RThi[kk * 136 + n]) + b2f(RTlo[kk * 136 + n]));
  }

  {
    s8v Shi[4], Slo[4];
#pragma unroll
    for (int ks = 0; ks < 4; ++ks) {
      int m = mr + c_;
      int k0 = ks * 32 + g_ * 8;
#pragma unroll
      for (int i = 0; i < 8; ++i) {
        Shi[ks][i] = RThi[(k0 + i) * 136 + m];
        Slo[ks][i] = RTlo[(k0 + i) * 136 + m];
      }
    }
    f4v acc[6];
#pragma unroll
    for (int nt = 0; nt < 6; ++nt) acc[nt] = (f4v){0.f, 0.f, 0.f, 0.f};
#pragma unroll
    for (int ks = 0; ks < 4; ++ks) {
#pragma unroll
      for (int nt = 0; nt < 6; ++nt) {
        s8v bh, bl;
#pragma unroll
        for (int i = 0; i < 8; ++i) {
          float v = sW2[(ks * 32 + g_ * 8 + i) * 96 + nt * 16 + c_];
          short h = f2b(v);
          bh[i] = h;
          bl[i] = f2b(v - b2f(h));
        }
        acc[nt] = MFMA(Shi[ks], bh, acc[nt]);
        acc[nt] = MFMA(Slo[ks], bh, acc[nt]);
        acc[nt] = MFMA(Shi[ks], bl, acc[nt]);
      }
    }
#pragma unroll
    for (int nt = 0; nt < 6; ++nt)
#pragma unroll
      for (int r = 0; r < 4; ++r)
        w2kout[(mr + g_ * 4 + r) * 96 + nt * 16 + c_] = f2b(acc[nt][r]);
  }
}

// ---------------------------------------------------------------------------
// Kernel 2: fused pipeline. 8 waves = 4 row-groups x 2 col-groups; each wave
// owns 32 rows x half the output columns. ALL weight fragments live in VGPRs
// (loaded once from global); LDS holds only activations (X / H|H2 / Z).
// X(t+1) prefetched into registers during stage1, written to sX after b1.
// 4 barriers/tile.
// ---------------------------------------------------------------------------
__global__ __launch_bounds__(512, 2) void koop_main(
    const float* __restrict__ xg, const float* __restrict__ w1g,
    const float* __restrict__ b1g, const float* __restrict__ i1g,
    const float* __restrict__ bi1g, const float* __restrict__ i2g,
    const float* __restrict__ bi2g, const short* __restrict__ m1g,
    const short* __restrict__ w2kg, float* __restrict__ outg) {
  extern __shared__ __align__(16) char smem[];
  short* sX = (short*)smem;            // 128 x 72   (stride 144B)
  short* sH = (short*)smem + 9216;     // 128 x 104  (stride 208B) — reused as H2
  short* sZ = (short*)smem + 22528;    // 128 x 136  (stride 272B)

  const int tid = threadIdx.x;
  const int lane = tid & 63, wid = tid >> 6;
  const int c_ = lane & 15, g_ = lane >> 4;
  const int rg = wid >> 1, cg = wid & 1;
  const int m0 = rg * 32;

  // ---- weight fragments -> registers (once per kernel) ----
  s8v rW1[3][2], rM1[4][2], rW2K[4][3], rI1[3][4], rI2[2][3];
  float bH[3], bH2[3], bO[2];
#pragma unroll
  for (int j = 0; j < 3; ++j) {
    const int n = (cg * 3 + j) * 16 + c_;
    bH[j]  = b1g[n];
    bH2[j] = bi1g[n];
#pragma unroll
    for (int ks = 0; ks < 2; ++ks) {
      const float* p = w1g + n * 64 + ks * 32 + g_ * 8;
      rW1[j][ks] = pack8(*(const f4v*)p, *(const f4v*)(p + 4));
    }
#pragma unroll
    for (int ks = 0; ks < 4; ++ks) {
      const float* p = i1g + n * 128 + ks * 32 + g_ * 8;
      rI1[j][ks] = pack8(*(const f4v*)p, *(const f4v*)(p + 4));
    }
  }
#pragma unroll
  for (int j = 0; j < 4; ++j) {
    const int n = (cg * 4 + j) * 16 + c_;
#pragma unroll
    for (int ks = 0; ks < 2; ++ks)
      rM1[j][ks] = *(const s8v*)(m1g + n * 64 + ks * 32 + g_ * 8);
#pragma unroll
    for (int ks = 0; ks < 3; ++ks)
      rW2K[j][ks] = *(const s8v*)(w2kg + n * 96 + ks * 32 + g_ * 8);
  }
#pragma unroll
  for (int j = 0; j < 2; ++j) {
    const int n = (cg * 2 + j) * 16 + c_;
    bO[j] = bi2g[n];
#pragma unroll
    for (int ks = 0; ks < 3; ++ks) {
      const float* p = i2g + n * 96 + ks * 32 + g_ * 8;
      rI2[j][ks] = pack8(*(const f4v*)p, *(const f4v*)(p + 4));
    }
  }

  const int xr = tid >> 2, xq = tid & 3;   // X staging map: row, 16-float chunk

  // ---- prologue: stage X(tile0) ----
  int tile = blockIdx.x;
  {
    const float* src = xg + ((size_t)tile * 128 + xr) * 64 + xq * 16;
    f4v v0 = *(const f4v*)src, v1 = *(const f4v*)(src + 4);
    f4v v2 = *(const f4v*)(src + 8), v3 = *(const f4v*)(src + 12);
    *(s8v*)(sX + xr * 72 + xq * 16)     = pack8(v0, v1);
    *(s8v*)(sX + xr * 72 + xq * 16 + 8) = pack8(v2, v3);
  }
  __syncthreads();

  for (; tile < TILES; tile += 256) {
    const int nxt = tile + 256;
    f4v xv0, xv1, xv2, xv3;
    if (nxt < TILES) {                       // issue next-tile loads (T14)
      const float* src = xg + ((size_t)nxt * 128 + xr) * 64 + xq * 16;
      xv0 = *(const f4v*)src;       xv1 = *(const f4v*)(src + 4);
      xv2 = *(const f4v*)(src + 8); xv3 = *(const f4v*)(src + 12);
    }

    // ---- stage 1: H = relu(X @ W1^T + b1), half-cols per wave ----
    s8v ax[2][2];
#pragma unroll
    for (int mi = 0; mi < 2; ++mi) {
      const int m = m0 + mi * 16;
#pragma unroll
      for (int ks = 0; ks < 2; ++ks) ax[mi][ks] = ldfrag(sX, m, ks * 32, 72);
#pragma unroll
      for (int j = 0; j < 3; ++j) {
        f4v acc = (f4v){bH[j], bH[j], bH[j], bH[j]};
        acc = MFMA(ax[mi][0], rW1[j][0], acc);
        acc = MFMA(ax[mi][1], rW1[j][1], acc);
#pragma unroll
        for (int r = 0; r < 4; ++r) {
          float v = acc[r]; v = v > 0.f ? v : 0.f;
          sH[(m + g_ * 4 + r) * 104 + (cg * 3 + j) * 16 + c_] = f2b(v);
        }
      }
    }
    __syncthreads();  // b1: sH ready; all sX reads done

    if (nxt < TILES) {                       // sX now dead -> write X(t+1)
      *(s8v*)(sX + xr * 72 + xq * 16)     = pack8(xv0, xv1);
      *(s8v*)(sX + xr * 72 + xq * 16 + 8) = pack8(xv2, xv3);
    }

    // ---- stage 2: Z = X @ M1^T + H @ W2K^T (X from regs) ----
#pragma unroll
    for (int mi = 0; mi < 2; ++mi) {
      const int m = m0 + mi * 16;
      s8v ah0 = ldfrag(sH, m, 0, 104);
      s8v ah1 = ldfrag(sH, m, 32, 104);
      s8v ah2 = ldfrag(sH, m, 64, 104);
#pragma unroll
      for (int j = 0; j < 4; ++j) {
        f4v acc = (f4v){0.f, 0.f, 0.f, 0.f};
        acc = MFMA(ax[mi][0], rM1[j][0], acc);
        acc = MFMA(ax[mi][1], rM1[j][1], acc);
        acc = MFMA(ah0, rW2K[j][0], acc);
        acc = MFMA(ah1, rW2K[j][1], acc);
        acc = MFMA(ah2, rW2K[j][2], acc);
#pragma unroll
        for (int r = 0; r < 4; ++r)
          sZ[(m + g_ * 4 + r) * 136 + (cg * 4 + j) * 16 + c_] = f2b(acc[r]);
      }
    }
    __syncthreads();  // b2: sZ ready; sH dead

    // ---- stage 3: H2 = relu(Z @ I1^T + bi1) -> sH region ----
#pragma unroll
    for (int mi = 0; mi < 2; ++mi) {
      const int m = m0 + mi * 16;
      s8v az0 = ldfrag(sZ, m, 0, 136);
      s8v az1 = ldfrag(sZ, m, 32, 136);
      s8v az2 = ldfrag(sZ, m, 64, 136);
      s8v az3 = ldfrag(sZ, m, 96, 136);
#pragma unroll
      for (int j = 0; j < 3; ++j) {
        f4v acc = (f4v){bH2[j], bH2[j], bH2[j], bH2[j]};
        acc = MFMA(az0, rI1[j][0], acc);
        acc = MFMA(az1, rI1[j][1], acc);
        acc = MFMA(az2, rI1[j][2], acc);
        acc = MFMA(az3, rI1[j][3], acc);
#pragma unroll
        for (int r = 0; r < 4; ++r) {
          float v = acc[r]; v = v > 0.f ? v : 0.f;
          sH[(m + g_ * 4 + r) * 104 + (cg * 3 + j) * 16 + c_] = f2b(v);
        }
      }
    }
    __syncthreads();  // b3: H2 ready

    // ---- stage 4: OUT = H2 @ I2^T + bi2 -> global ----
#pragma unroll
    for (int mi = 0; mi < 2; ++mi) {
      const int m = m0 + mi * 16;
      s8v a0 = ldfrag(sH, m, 0, 104);
      s8v a1 = ldfrag(sH, m, 32, 104);
      s8v a2 = ldfrag(sH, m, 64, 104);
#pragma unroll
      for (int j = 0; j < 2; ++j) {
        f4v acc = (f4v){bO[j], bO[j], bO[j], bO[j]};
        acc = MFMA(a0, rI2[j][0], acc);
        acc = MFMA(a1, rI2[j][1], acc);
        acc = MFMA(a2, rI2[j][2], acc);
#pragma unroll
        for (int r = 0; r < 4; ++r)
          outg[((size_t)tile * 128 + m + g_ * 4 + r) * 64 + (cg * 2 + j) * 16 + c_] = acc[r];
      }
    }
    __syncthreads();  // b4: sH2 reads + sX(t+1) writes complete
  }
}

#define PREP_LDS (128 * 136 * 2 * 2 + 128 * 96 * 4 + 130 * 4)   // 119304 B
#define MAIN_LDS ((9216 + 13312 + 17408) * 2)                    // 79872 B

extern "C" void kernel_launch(void* const* d_in, const int* in_sizes, int n_in,
                              void* d_out, int out_size, void* d_ws, size_t ws_size,
                              hipStream_t stream) {
  (void)in_sizes; (void)n_in; (void)out_size; (void)ws_size;
  const float* t     = (const float*)d_in[0];
  const float* x     = (const float*)d_in[1];
  const float* A     = (const float*)d_in[2];
  const float* phiW1 = (const float*)d_in[3];
  const float* phib1 = (const float*)d_in[4];
  const float* phiW2 = (const float*)d_in[5];
  const float* invW1 = (const float*)d_in[6];
  const float* invb1 = (const float*)d_in[7];
  const float* invW2 = (const float*)d_in[8];
  const float* invb2 = (const float*)d_in[9];
  float* out = (float*)d_out;

  short* m1w = (short*)d_ws;            // [128][64]  bf16
  short* w2k = m1w + 128 * 64;          // [128][96]  bf16

  (void)hipFuncSetAttribute((const void*)koop_prep,
                            hipFuncAttributeMaxDynamicSharedMemorySize, PREP_LDS);
  (void)hipFuncSetAttribute((const void*)koop_main,
                            hipFuncAttributeMaxDynamicSharedMemorySize, MAIN_LDS);

  koop_prep<<<1, 512, PREP_LDS, stream>>>(t, A, phiW2, m1w, w2k);
  koop_main<<<256, 512, MAIN_LDS, stream>>>(x, phiW1, phib1, invW1, invb1,
                                            invW2, invb2, m1w, w2k, out);
}

// Round 4
// 144.225 us; speedup vs baseline: 1.2303x; 1.2303x over previous
//
#include <hip/hip_runtime.h>

#define BTOT    524288
#define NT64    8192           // BTOT / 64  (64-row tiles)
#define GRID    512            // 2 blocks/CU
#define TN      6              // Taylor order for expm (norm<=0.5 -> rem ~1.5e-6)

typedef __attribute__((ext_vector_type(8))) short s8v;   // 8 x bf16 bits
typedef __attribute__((ext_vector_type(4))) float f4v;

#define MFMA(a,b,c) __builtin_amdgcn_mfma_f32_16x16x32_bf16((a),(b),(c),0,0,0)
#define KEEP(x) asm volatile("" : "+v"(x))

__device__ __forceinline__ short f2b(float f) {          // f32 -> bf16 (RNE)
  union { float f; unsigned u; } v; v.f = f;
  unsigned r = v.u + 0x7fffu + ((v.u >> 16) & 1u);
  return (short)(r >> 16);
}
__device__ __forceinline__ float b2f(short s) {
  union { float f; unsigned u; } v; v.u = ((unsigned)(unsigned short)s) << 16;
  return v.f;
}
__device__ __forceinline__ s8v pack8(f4v u, f4v v) {
  s8v w;
  w[0] = f2b(u[0]); w[1] = f2b(u[1]); w[2] = f2b(u[2]); w[3] = f2b(u[3]);
  w[4] = f2b(v[0]); w[5] = f2b(v[1]); w[6] = f2b(v[2]); w[7] = f2b(v[3]);
  return w;
}

// MFMA fragment load from a padded row-major LDS tile (prep kernel only)
__device__ __forceinline__ s8v ldfrag(const short* base, int row0, int kbase, int stride) {
  const int l = threadIdx.x & 63;
  return *(const s8v*)(base + (row0 + (l & 15)) * stride + kbase + (l >> 4) * 8);
}

// ---- ws layout (shorts): fragment-linear packed weights ----
// pM1   [0,      8192)   K[:, :64]      jj in 0..7, KS=2
// pI1   [8192,  20480)   inv_W1 [96][128] jj 0..5, KS=4
// pW1   [20480, 26624)   phi_W1 [96][64]  jj 0..5, KS=2
// pW2K  [26624, 38912)   K@phi_W2 [128][96] jj 0..7, KS=3
// pI2   [38912, 45056)   inv_W2 [64][96]  jj 0..3, KS=3
#define WS_M1   0
#define WS_I1   8192
#define WS_W1   20480
#define WS_W2K  26624
#define WS_I2   38912

// frag-linear index for element (n = out col of B^T, k) with KS = K/32 chunks
__device__ __forceinline__ int fragidx(int n, int k, int KS) {
  int jj = n >> 4, ks = k >> 5;
  int l = (n & 15) | (((k >> 3) & 3) << 4);
  return ((jj * KS + ks) * 64 + l) * 8 + (k & 7);
}

// ---------------------------------------------------------------------------
// Kernel 1: expm(A*t/24) via scaling+squaring Taylor (split-bf16 MFMA), then
// emit ALL weights as bf16 fragment-linear buffers in ws.
// ---------------------------------------------------------------------------
__global__ __launch_bounds__(512, 2) void koop_prep(
    const float* __restrict__ tptr, const float* __restrict__ Ag,
    const float* __restrict__ W2g, const float* __restrict__ w1g,
    const float* __restrict__ i1g, const float* __restrict__ i2g,
    short* __restrict__ wsp) {
  extern __shared__ __align__(16) char smem[];
  short* RThi = (short*)smem;              // [128][136]  (RT[col][row] of R)
  short* RTlo = RThi + 128 * 136;          // [128][136]
  float* sW2  = (float*)(RTlo + 128 * 136);// [128][96] f32
  float* sred = sW2 + 128 * 96;            // [130]
  float* scratch = (float*)smem;           // [128][128] f32 alias (dead before RT writes)

  const int tid = threadIdx.x;
  const int lane = tid & 63, wid = tid >> 6;
  const int c_ = lane & 15, g_ = lane >> 4;
  const int mr = wid * 16;

  // raw-weight fragment packing (independent of expm)
  for (int e = tid; e < 6144; e += 512) {          // W1 [96][64]
    wsp[WS_W1 + fragidx(e >> 6, e & 63, 2)] = f2b(w1g[e]);
  }
  for (int e = tid; e < 12288; e += 512) {         // I1 [96][128]
    wsp[WS_I1 + fragidx(e >> 7, e & 127, 4)] = f2b(i1g[e]);
  }
  for (int e = tid; e < 6144; e += 512) {          // I2 [64][96]
    wsp[WS_I2 + fragidx(e / 96, e % 96, 3)] = f2b(i2g[e]);
  }

  const float s = tptr[0] * (1.0f / 24.0f);
  for (int i = tid; i < 128 * 128; i += 512) scratch[i] = Ag[i] * s;
  for (int i = tid; i < 128 * 96;  i += 512) sW2[i] = W2g[i];
  __syncthreads();

  if (tid < 128) {
    float su = 0.f;
    for (int j = 0; j < 128; ++j) su += fabsf(scratch[tid * 128 + j]);
    sred[tid] = su;
  }
  __syncthreads();
  if (tid == 0) {
    float m = 0.f;
    for (int i = 0; i < 128; ++i) m = fmaxf(m, sred[i]);
    int j = 0; float sc = 1.f;
    while (m > 0.5f && j < 20) { m *= 0.5f; sc *= 0.5f; ++j; }
    sred[128] = (float)j; sred[129] = sc;
  }
  __syncthreads();
  const int jsq = (int)sred[128];
  const float sc = sred[129];

  s8v Ahi[4], Alo[4];
#pragma unroll
  for (int ks = 0; ks < 4; ++ks) {
    const float* p = scratch + (mr + c_) * 128 + ks * 32 + g_ * 8;
    f4v u = *(const f4v*)p, v = *(const f4v*)(p + 4);
    float vals[8] = {u[0], u[1], u[2], u[3], v[0], v[1], v[2], v[3]};
#pragma unroll
    for (int i = 0; i < 8; ++i) {
      float y = vals[i] * sc;
      short h = f2b(y);
      Ahi[ks][i] = h;
      Alo[ks][i] = f2b(y - b2f(h));
    }
  }
  float yv[32];
#pragma unroll
  for (int e = 0; e < 32; ++e) yv[e] = scratch[tid * 32 + e];
  __syncthreads();

#pragma unroll
  for (int e = 0; e < 32; ++e) {
    int idx = tid * 32 + e;
    int r = idx >> 7, c = idx & 127;
    float v = yv[e] * sc * (1.0f / TN) + ((r == c) ? 1.0f : 0.0f);
    short h = f2b(v);
    RThi[c * 136 + r] = h;
    RTlo[c * 136 + r] = f2b(v - b2f(h));
  }
  __syncthreads();

  for (int k = TN - 1; k >= 1; --k) {
    f4v acc[8];
#pragma unroll
    for (int nt = 0; nt < 8; ++nt) acc[nt] = (f4v){0.f, 0.f, 0.f, 0.f};
#pragma unroll
    for (int ks = 0; ks < 4; ++ks) {
#pragma unroll
      for (int nt = 0; nt < 8; ++nt) {
        s8v bh = ldfrag(RThi, nt * 16, ks * 32, 136);
        s8v bl = ldfrag(RTlo, nt * 16, ks * 32, 136);
        acc[nt] = MFMA(Ahi[ks], bh, acc[nt]);
        acc[nt] = MFMA(Alo[ks], bh, acc[nt]);
        acc[nt] = MFMA(Ahi[ks], bl, acc[nt]);
      }
    }
    __syncthreads();
    const float invk = 1.0f / (float)k;
#pragma unroll
    for (int nt = 0; nt < 8; ++nt)
#pragma unroll
      for (int r = 0; r < 4; ++r) {
        int row = mr + g_ * 4 + r, col = nt * 16 + c_;
        float v = acc[nt][r] * invk + ((row == col) ? 1.0f : 0.0f);
        short h = f2b(v);
        RThi[col * 136 + row] = h;
        RTlo[col * 136 + row] = f2b(v - b2f(h));
      }
    __syncthreads();
  }

  for (int it = 0; it < jsq; ++it) {
    s8v Shi[4], Slo[4];
#pragma unroll
    for (int ks = 0; ks < 4; ++ks) {
      int m = mr + c_;
      int k0 = ks * 32 + g_ * 8;
#pragma unroll
      for (int i = 0; i < 8; ++i) {
        Shi[ks][i] = RThi[(k0 + i) * 136 + m];
        Slo[ks][i] = RTlo[(k0 + i) * 136 + m];
      }
    }
    f4v acc[8];
#pragma unroll
    for (int nt = 0; nt < 8; ++nt) acc[nt] = (f4v){0.f, 0.f, 0.f, 0.f};
#pragma unroll
    for (int ks = 0; ks < 4; ++ks) {
#pragma unroll
      for (int nt = 0; nt < 8; ++nt) {
        s8v bh = ldfrag(RThi, nt * 16, ks * 32, 136);
        s8v bl = ldfrag(RTlo, nt * 16, ks * 32, 136);
        acc[nt] = MFMA(Shi[ks], bh, acc[nt]);
        acc[nt] = MFMA(Slo[ks], bh, acc[nt]);
        acc[nt] = MFMA(Shi[ks], bl, acc[nt]);
      }
    }
    __syncthreads();
#pragma unroll
    for (int nt = 0; nt < 8; ++nt)
#pragma unroll
      for (int r = 0; r < 4; ++r) {
        int row = mr + g_ * 4 + r, col = nt * 16 + c_;
        float v = acc[nt][r];
        short h = f2b(v);
        RThi[col * 136 + row] = h;
        RTlo[col * 136 + row] = f2b(v - b2f(h));
      }
    __syncthreads();
  }

  // M1 = K[:, :64] -> frag-linear
  for (int e = tid; e < 128 * 64; e += 512) {
    int n = e >> 6, kk = e & 63;
    float v = b2f(RThi[kk * 136 + n]) + b2f(RTlo[kk * 136 + n]);
    wsp[WS_M1 + fragidx(n, kk, 2)] = f2b(v);
  }

  // W2K = K @ phi_W2 -> frag-linear
  {
    s8v Shi[4], Slo[4];
#pragma unroll
    for (int ks = 0; ks < 4; ++ks) {
      int m = mr + c_;
      int k0 = ks * 32 + g_ * 8;
#pragma unroll
      for (int i = 0; i < 8; ++i) {
        Shi[ks][i] = RThi[(k0 + i) * 136 + m];
        Slo[ks][i] = RTlo[(k0 + i) * 136 + m];
      }
    }
    f4v acc[6];
#pragma unroll
    for (int nt = 0; nt < 6; ++nt) acc[nt] = (f4v){0.f, 0.f, 0.f, 0.f};
#pragma unroll
    for (int ks = 0; ks < 4; ++ks) {
#pragma unroll
      for (int nt = 0; nt < 6; ++nt) {
        s8v bh, bl;
#pragma unroll
        for (int i = 0; i < 8; ++i) {
          float v = sW2[(ks * 32 + g_ * 8 + i) * 96 + nt * 16 + c_];
          short h = f2b(v);
          bh[i] = h;
          bl[i] = f2b(v - b2f(h));
        }
        acc[nt] = MFMA(Shi[ks], bh, acc[nt]);
        acc[nt] = MFMA(Slo[ks], bh, acc[nt]);
        acc[nt] = MFMA(Shi[ks], bl, acc[nt]);
      }
    }
#pragma unroll
    for (int nt = 0; nt < 6; ++nt)
#pragma unroll
      for (int r = 0; r < 4; ++r)
        wsp[WS_W2K + fragidx(mr + g_ * 4 + r, nt * 16 + c_, 3)] = f2b(acc[nt][r]);
  }
}

// ---------------------------------------------------------------------------
// Kernel 2: fused pipeline. 256 threads (4 waves = 2 row-groups x 2 col-
// groups), 64-row tiles, 2 blocks/CU (independent barrier domains overlap).
// W1/W2K/I2 fragments in VGPR (96 regs, pinned); M1/I1 frag-linear in LDS.
// Activations X/H/Z frag-linear in LDS: all frag reads conflict-free b128.
// ---------------------------------------------------------------------------
__global__ __launch_bounds__(256, 2) void koop_main(
    const float* __restrict__ xg, const float* __restrict__ b1g,
    const float* __restrict__ bi1g, const float* __restrict__ bi2g,
    const short* __restrict__ wsp, float* __restrict__ outg) {
  extern __shared__ __align__(16) char smem[];
  short* sM1 = (short*)smem;        // 8192  (16 chunks of 512)
  short* sI1 = sM1 + 8192;          // 12288 (24 chunks)
  short* sX  = sI1 + 12288;         // 4096  (8 chunks)
  short* sH  = sX + 4096;           // 6144  (12 chunks)  H, then H2
  short* sZ  = sH + 6144;           // 8192  (16 chunks)

  const int tid = threadIdx.x;
  const int lane = tid & 63, wid = tid >> 6;
  const int c_ = lane & 15, g_ = lane >> 4;
  const int rg = wid >> 1, cg = wid & 1;

  // ---- copy M1+I1 frag buffers to LDS (contiguous 40KB) ----
  for (int i = tid; i < (8192 + 12288) / 8; i += 256)
    ((f4v*)sM1)[i] = ((const f4v*)(wsp + WS_M1))[i];

  // ---- VGPR weights (pinned; ~96 regs) ----
  f4v wW1[3][2], wW2K[4][3], wI2[2][3];
  float bH[3], bH2[3], bO[2];
#pragma unroll
  for (int j = 0; j < 3; ++j) {
    bH[j]  = b1g[(cg * 3 + j) * 16 + c_];
    bH2[j] = bi1g[(cg * 3 + j) * 16 + c_];
#pragma unroll
    for (int ks = 0; ks < 2; ++ks) {
      wW1[j][ks] = *(const f4v*)(wsp + WS_W1 + (((cg * 3 + j) * 2 + ks) * 64 + lane) * 8);
      KEEP(wW1[j][ks]);
    }
  }
#pragma unroll
  for (int j = 0; j < 4; ++j)
#pragma unroll
    for (int ks = 0; ks < 3; ++ks) {
      wW2K[j][ks] = *(const f4v*)(wsp + WS_W2K + (((cg * 4 + j) * 3 + ks) * 64 + lane) * 8);
      KEEP(wW2K[j][ks]);
    }
#pragma unroll
  for (int j = 0; j < 2; ++j) {
    bO[j] = bi2g[(cg * 2 + j) * 16 + c_];
#pragma unroll
    for (int ks = 0; ks < 3; ++ks) {
      wI2[j][ks] = *(const f4v*)(wsp + WS_I2 + (((cg * 2 + j) * 3 + ks) * 64 + lane) * 8);
      KEEP(wI2[j][ks]);
    }
  }

  // X staging slot decode: slot s in [0,512): chunk = s>>6 = ((rg*2+mi)*2+ks)
  const int s0 = tid, s1 = tid + 256;
  int srow[2], sk0[2];
#pragma unroll
  for (int q = 0; q < 2; ++q) {
    int s = q ? s1 : s0;
    int cid = s >> 6, sl = s & 63;
    srow[q] = (cid >> 2) * 32 + ((cid >> 1) & 1) * 16 + (sl & 15);
    sk0[q]  = (cid & 1) * 32 + (sl >> 4) * 8;
  }

  // ---- prologue: stage X(tile0) ----
  int tile = blockIdx.x;
  {
    const float* p0 = xg + ((size_t)tile * 64 + srow[0]) * 64 + sk0[0];
    const float* p1 = xg + ((size_t)tile * 64 + srow[1]) * 64 + sk0[1];
    *(s8v*)(sX + s0 * 8) = pack8(*(const f4v*)p0, *(const f4v*)(p0 + 4));
    *(s8v*)(sX + s1 * 8) = pack8(*(const f4v*)p1, *(const f4v*)(p1 + 4));
  }
  __syncthreads();

  for (; tile < NT64; tile += GRID) {
    const int nxt = tile + GRID;
    f4v pv0, pv1, pv2, pv3;
    if (nxt < NT64) {                         // issue next-tile loads (T14)
      const float* p0 = xg + ((size_t)nxt * 64 + srow[0]) * 64 + sk0[0];
      const float* p1 = xg + ((size_t)nxt * 64 + srow[1]) * 64 + sk0[1];
      pv0 = *(const f4v*)p0; pv1 = *(const f4v*)(p0 + 4);
      pv2 = *(const f4v*)p1; pv3 = *(const f4v*)(p1 + 4);
    }

    // ---- stage 1: H = relu(X @ W1^T + b1) ----
    s8v ax[2][2];
#pragma unroll
    for (int mi = 0; mi < 2; ++mi) {
#pragma unroll
      for (int ks = 0; ks < 2; ++ks)
        ax[mi][ks] = *(const s8v*)(sX + (((rg * 2 + mi) * 2 + ks) * 64 + lane) * 8);
#pragma unroll
      for (int j = 0; j < 3; ++j) {
        f4v acc = (f4v){bH[j], bH[j], bH[j], bH[j]};
        acc = MFMA(ax[mi][0], __builtin_bit_cast(s8v, wW1[j][0]), acc);
        acc = MFMA(ax[mi][1], __builtin_bit_cast(s8v, wW1[j][1]), acc);
        const int cb = (cg * 3 + j) * 16;
        const int ks3 = cb >> 5, hb = ((cb >> 3) & 3) + (c_ >> 3);
#pragma unroll
        for (int r = 0; r < 4; ++r) {
          float v = acc[r]; v = v > 0.f ? v : 0.f;
          sH[(((rg * 2 + mi) * 3 + ks3) * 64 + ((g_ * 4 + r) | (hb << 4))) * 8 + (c_ & 7)] = f2b(v);
        }
      }
    }
    __syncthreads();  // b1: sH ready; all sX reads done

    if (nxt < NT64) {                         // sX dead -> write X(t+1)
      *(s8v*)(sX + s0 * 8) = pack8(pv0, pv1);
      *(s8v*)(sX + s1 * 8) = pack8(pv2, pv3);
    }

    // ---- stage 2: Z = X @ M1^T + H @ W2K^T ----
#pragma unroll
    for (int mi = 0; mi < 2; ++mi) {
      s8v ah0 = *(const s8v*)(sH + (((rg * 2 + mi) * 3 + 0) * 64 + lane) * 8);
      s8v ah1 = *(const s8v*)(sH + (((rg * 2 + mi) * 3 + 1) * 64 + lane) * 8);
      s8v ah2 = *(const s8v*)(sH + (((rg * 2 + mi) * 3 + 2) * 64 + lane) * 8);
#pragma unroll
      for (int j = 0; j < 4; ++j) {
        s8v m0 = *(const s8v*)(sM1 + (((cg * 4 + j) * 2 + 0) * 64 + lane) * 8);
        s8v m1 = *(const s8v*)(sM1 + (((cg * 4 + j) * 2 + 1) * 64 + lane) * 8);
        f4v acc = (f4v){0.f, 0.f, 0.f, 0.f};
        acc = MFMA(ax[mi][0], m0, acc);
        acc = MFMA(ax[mi][1], m1, acc);
        acc = MFMA(ah0, __builtin_bit_cast(s8v, wW2K[j][0]), acc);
        acc = MFMA(ah1, __builtin_bit_cast(s8v, wW2K[j][1]), acc);
        acc = MFMA(ah2, __builtin_bit_cast(s8v, wW2K[j][2]), acc);
        const int cb = (cg * 4 + j) * 16;
        const int ks4 = cb >> 5, hb = ((cb >> 3) & 3) + (c_ >> 3);
#pragma unroll
        for (int r = 0; r < 4; ++r)
          sZ[(((rg * 2 + mi) * 4 + ks4) * 64 + ((g_ * 4 + r) | (hb << 4))) * 8 + (c_ & 7)] = f2b(acc[r]);
      }
    }
    __syncthreads();  // b2: sZ ready; sH dead

    // ---- stage 3: H2 = relu(Z @ I1^T + bi1) -> sH region ----
#pragma unroll
    for (int mi = 0; mi < 2; ++mi) {
      s8v az[4];
#pragma unroll
      for (int ks = 0; ks < 4; ++ks)
        az[ks] = *(const s8v*)(sZ + (((rg * 2 + mi) * 4 + ks) * 64 + lane) * 8);
#pragma unroll
      for (int j = 0; j < 3; ++j) {
        f4v acc = (f4v){bH2[j], bH2[j], bH2[j], bH2[j]};
#pragma unroll
        for (int ks = 0; ks < 4; ++ks) {
          s8v bfrag = *(const s8v*)(sI1 + (((cg * 3 + j) * 4 + ks) * 64 + lane) * 8);
          acc = MFMA(az[ks], bfrag, acc);
        }
        const int cb = (cg * 3 + j) * 16;
        const int ks3 = cb >> 5, hb = ((cb >> 3) & 3) + (c_ >> 3);
#pragma unroll
        for (int r = 0; r < 4; ++r) {
          float v = acc[r]; v = v > 0.f ? v : 0.f;
          sH[(((rg * 2 + mi) * 3 + ks3) * 64 + ((g_ * 4 + r) | (hb << 4))) * 8 + (c_ & 7)] = f2b(v);
        }
      }
    }
    __syncthreads();  // b3: H2 ready

    // ---- stage 4: OUT = H2 @ I2^T + bi2 -> global ----
#pragma unroll
    for (int mi = 0; mi < 2; ++mi) {
      s8v a0 = *(const s8v*)(sH + (((rg * 2 + mi) * 3 + 0) * 64 + lane) * 8);
      s8v a1 = *(const s8v*)(sH + (((rg * 2 + mi) * 3 + 1) * 64 + lane) * 8);
      s8v a2 = *(const s8v*)(sH + (((rg * 2 + mi) * 3 + 2) * 64 + lane) * 8);
#pragma unroll
      for (int j = 0; j < 2; ++j) {
        f4v acc = (f4v){bO[j], bO[j], bO[j], bO[j]};
        acc = MFMA(a0, __builtin_bit_cast(s8v, wI2[j][0]), acc);
        acc = MFMA(a1, __builtin_bit_cast(s8v, wI2[j][1]), acc);
        acc = MFMA(a2, __builtin_bit_cast(s8v, wI2[j][2]), acc);
#pragma unroll
        for (int r = 0; r < 4; ++r)
          outg[((size_t)tile * 64 + rg * 32 + mi * 16 + g_ * 4 + r) * 64 +
               (cg * 2 + j) * 16 + c_] = acc[r];
      }
    }
    __syncthreads();  // b4: sH2 reads done before next stage1 writes
  }
}

#define PREP_LDS (128 * 136 * 2 * 2 + 128 * 96 * 4 + 130 * 4)   // 119304 B
#define MAIN_LDS ((8192 + 12288 + 4096 + 6144 + 8192) * 2)      // 77824 B

extern "C" void kernel_launch(void* const* d_in, const int* in_sizes, int n_in,
                              void* d_out, int out_size, void* d_ws, size_t ws_size,
                              hipStream_t stream) {
  (void)in_sizes; (void)n_in; (void)out_size; (void)ws_size;
  const float* t     = (const float*)d_in[0];
  const float* x     = (const float*)d_in[1];
  const float* A     = (const float*)d_in[2];
  const float* phiW1 = (const float*)d_in[3];
  const float* phib1 = (const float*)d_in[4];
  const float* phiW2 = (const float*)d_in[5];
  const float* invW1 = (const float*)d_in[6];
  const float* invb1 = (const float*)d_in[7];
  const float* invW2 = (const float*)d_in[8];
  const float* invb2 = (const float*)d_in[9];
  float* out = (float*)d_out;
  short* wsp = (short*)d_ws;

  (void)hipFuncSetAttribute((const void*)koop_prep,
                            hipFuncAttributeMaxDynamicSharedMemorySize, PREP_LDS);
  (void)hipFuncSetAttribute((const void*)koop_main,
                            hipFuncAttributeMaxDynamicSharedMemorySize, MAIN_LDS);

  koop_prep<<<1, 512, PREP_LDS, stream>>>(t, A, phiW2, phiW1, invW1, invW2, wsp);
  koop_main<<<GRID, 256, MAIN_LDS, stream>>>(x, phib1, invb1, invb2, wsp, out);
}

// Round 5
// 139.647 us; speedup vs baseline: 1.2706x; 1.0328x over previous
//
#include <hip/hip_runtime.h>

#define BTOT    524288
#define NT64    8192           // BTOT / 64  (64-row tiles)
#define GRID    512            // 2 blocks/CU
#define TN      6              // Taylor order for expm (norm<=0.5 -> rem ~1.5e-6)

#define SX 72                  // LDS row strides (shorts): 8*odd -> 16B-aligned, balanced banks
#define SH 104
#define SZ 136

typedef __attribute__((ext_vector_type(8))) short s8v;   // 8 x bf16 bits
typedef __attribute__((ext_vector_type(4))) short s4v;   // 4 x bf16 bits
typedef __attribute__((ext_vector_type(4))) float f4v;

#define MFMA(a,b,c) __builtin_amdgcn_mfma_f32_16x16x32_bf16((a),(b),(c),0,0,0)
#define KEEP(x) asm volatile("" : "+v"(x))

__device__ __forceinline__ short f2b(float f) {          // f32 -> bf16 (RNE)
  union { float f; unsigned u; } v; v.f = f;
  unsigned r = v.u + 0x7fffu + ((v.u >> 16) & 1u);
  return (short)(r >> 16);
}
__device__ __forceinline__ float b2f(short s) {
  union { float f; unsigned u; } v; v.u = ((unsigned)(unsigned short)s) << 16;
  return v.f;
}
__device__ __forceinline__ s8v pack8(f4v u, f4v v) {
  s8v w;
  w[0] = f2b(u[0]); w[1] = f2b(u[1]); w[2] = f2b(u[2]); w[3] = f2b(u[3]);
  w[4] = f2b(v[0]); w[5] = f2b(v[1]); w[6] = f2b(v[2]); w[7] = f2b(v[3]);
  return w;
}
__device__ __forceinline__ s4v pack4(f4v a) {
  s4v w; w[0]=f2b(a[0]); w[1]=f2b(a[1]); w[2]=f2b(a[2]); w[3]=f2b(a[3]); return w;
}
__device__ __forceinline__ s4v pack4r(f4v a) {
  s4v w;
  w[0]=f2b(fmaxf(a[0],0.f)); w[1]=f2b(fmaxf(a[1],0.f));
  w[2]=f2b(fmaxf(a[2],0.f)); w[3]=f2b(fmaxf(a[3],0.f));
  return w;
}

// MFMA fragment load from a padded row-major LDS tile (prep kernel only)
__device__ __forceinline__ s8v ldfrag(const short* base, int row0, int kbase, int stride) {
  const int l = threadIdx.x & 63;
  return *(const s8v*)(base + (row0 + (l & 15)) * stride + kbase + (l >> 4) * 8);
}

// Activation B-frag: lane holds Act[col0+(l&15)][kbase + (l>>4)*8 + i], i=0..7
__device__ __forceinline__ s8v ldact(const short* base, int col0, int kbase, int stride) {
  const int l = threadIdx.x & 63;
  return *(const s8v*)(base + (col0 + (l & 15)) * stride + kbase + (l >> 4) * 8);
}

// ---- ws layout (shorts): fragment-linear packed weights ----
#define WS_M1   0
#define WS_I1   8192
#define WS_W1   20480
#define WS_W2K  26624
#define WS_I2   38912

// frag-linear index for element (n = out-feature, k) with KS = K/32 chunks
__device__ __forceinline__ int fragidx(int n, int k, int KS) {
  int jj = n >> 4, ks = k >> 5;
  int l = (n & 15) | (((k >> 3) & 3) << 4);
  return ((jj * KS + ks) * 64 + l) * 8 + (k & 7);
}

// ---------------------------------------------------------------------------
// Kernel 1: expm(A*t/24) via scaling+squaring Taylor (split-bf16 MFMA), then
// emit ALL weights as bf16 fragment-linear buffers in ws.  (unchanged)
// ---------------------------------------------------------------------------
__global__ __launch_bounds__(512, 2) void koop_prep(
    const float* __restrict__ tptr, const float* __restrict__ Ag,
    const float* __restrict__ W2g, const float* __restrict__ w1g,
    const float* __restrict__ i1g, const float* __restrict__ i2g,
    short* __restrict__ wsp) {
  extern __shared__ __align__(16) char smem[];
  short* RThi = (short*)smem;              // [128][136]  (RT[col][row] of R)
  short* RTlo = RThi + 128 * 136;          // [128][136]
  float* sW2  = (float*)(RTlo + 128 * 136);// [128][96] f32
  float* sred = sW2 + 128 * 96;            // [130]
  float* scratch = (float*)smem;           // [128][128] f32 alias (dead before RT writes)

  const int tid = threadIdx.x;
  const int lane = tid & 63, wid = tid >> 6;
  const int c_ = lane & 15, g_ = lane >> 4;
  const int mr = wid * 16;

  for (int e = tid; e < 6144; e += 512)
    wsp[WS_W1 + fragidx(e >> 6, e & 63, 2)] = f2b(w1g[e]);
  for (int e = tid; e < 12288; e += 512)
    wsp[WS_I1 + fragidx(e >> 7, e & 127, 4)] = f2b(i1g[e]);
  for (int e = tid; e < 6144; e += 512)
    wsp[WS_I2 + fragidx(e / 96, e % 96, 3)] = f2b(i2g[e]);

  const float s = tptr[0] * (1.0f / 24.0f);
  for (int i = tid; i < 128 * 128; i += 512) scratch[i] = Ag[i] * s;
  for (int i = tid; i < 128 * 96;  i += 512) sW2[i] = W2g[i];
  __syncthreads();

  if (tid < 128) {
    float su = 0.f;
    for (int j = 0; j < 128; ++j) su += fabsf(scratch[tid * 128 + j]);
    sred[tid] = su;
  }
  __syncthreads();
  if (tid == 0) {
    float m = 0.f;
    for (int i = 0; i < 128; ++i) m = fmaxf(m, sred[i]);
    int j = 0; float sc = 1.f;
    while (m > 0.5f && j < 20) { m *= 0.5f; sc *= 0.5f; ++j; }
    sred[128] = (float)j; sred[129] = sc;
  }
  __syncthreads();
  const int jsq = (int)sred[128];
  const float sc = sred[129];

  s8v Ahi[4], Alo[4];
#pragma unroll
  for (int ks = 0; ks < 4; ++ks) {
    const float* p = scratch + (mr + c_) * 128 + ks * 32 + g_ * 8;
    f4v u = *(const f4v*)p, v = *(const f4v*)(p + 4);
    float vals[8] = {u[0], u[1], u[2], u[3], v[0], v[1], v[2], v[3]};
#pragma unroll
    for (int i = 0; i < 8; ++i) {
      float y = vals[i] * sc;
      short h = f2b(y);
      Ahi[ks][i] = h;
      Alo[ks][i] = f2b(y - b2f(h));
    }
  }
  float yv[32];
#pragma unroll
  for (int e = 0; e < 32; ++e) yv[e] = scratch[tid * 32 + e];
  __syncthreads();

#pragma unroll
  for (int e = 0; e < 32; ++e) {
    int idx = tid * 32 + e;
    int r = idx >> 7, c = idx & 127;
    float v = yv[e] * sc * (1.0f / TN) + ((r == c) ? 1.0f : 0.0f);
    short h = f2b(v);
    RThi[c * 136 + r] = h;
    RTlo[c * 136 + r] = f2b(v - b2f(h));
  }
  __syncthreads();

  for (int k = TN - 1; k >= 1; --k) {
    f4v acc[8];
#pragma unroll
    for (int nt = 0; nt < 8; ++nt) acc[nt] = (f4v){0.f, 0.f, 0.f, 0.f};
#pragma unroll
    for (int ks = 0; ks < 4; ++ks) {
#pragma unroll
      for (int nt = 0; nt < 8; ++nt) {
        s8v bh = ldfrag(RThi, nt * 16, ks * 32, 136);
        s8v bl = ldfrag(RTlo, nt * 16, ks * 32, 136);
        acc[nt] = MFMA(Ahi[ks], bh, acc[nt]);
        acc[nt] = MFMA(Alo[ks], bh, acc[nt]);
        acc[nt] = MFMA(Ahi[ks], bl, acc[nt]);
      }
    }
    __syncthreads();
    const float invk = 1.0f / (float)k;
#pragma unroll
    for (int nt = 0; nt < 8; ++nt)
#pragma unroll
      for (int r = 0; r < 4; ++r) {
        int row = mr + g_ * 4 + r, col = nt * 16 + c_;
        float v = acc[nt][r] * invk + ((row == col) ? 1.0f : 0.0f);
        short h = f2b(v);
        RThi[col * 136 + row] = h;
        RTlo[col * 136 + row] = f2b(v - b2f(h));
      }
    __syncthreads();
  }

  for (int it = 0; it < jsq; ++it) {
    s8v Shi[4], Slo[4];
#pragma unroll
    for (int ks = 0; ks < 4; ++ks) {
      int m = mr + c_;
      int k0 = ks * 32 + g_ * 8;
#pragma unroll
      for (int i = 0; i < 8; ++i) {
        Shi[ks][i] = RThi[(k0 + i) * 136 + m];
        Slo[ks][i] = RTlo[(k0 + i) * 136 + m];
      }
    }
    f4v acc[8];
#pragma unroll
    for (int nt = 0; nt < 8; ++nt) acc[nt] = (f4v){0.f, 0.f, 0.f, 0.f};
#pragma unroll
    for (int ks = 0; ks < 4; ++ks) {
#pragma unroll
      for (int nt = 0; nt < 8; ++nt) {
        s8v bh = ldfrag(RThi, nt * 16, ks * 32, 136);
        s8v bl = ldfrag(RTlo, nt * 16, ks * 32, 136);
        acc[nt] = MFMA(Shi[ks], bh, acc[nt]);
        acc[nt] = MFMA(Slo[ks], bh, acc[nt]);
        acc[nt] = MFMA(Shi[ks], bl, acc[nt]);
      }
    }
    __syncthreads();
#pragma unroll
    for (int nt = 0; nt < 8; ++nt)
#pragma unroll
      for (int r = 0; r < 4; ++r) {
        int row = mr + g_ * 4 + r, col = nt * 16 + c_;
        float v = acc[nt][r];
        short h = f2b(v);
        RThi[col * 136 + row] = h;
        RTlo[col * 136 + row] = f2b(v - b2f(h));
      }
    __syncthreads();
  }

  for (int e = tid; e < 128 * 64; e += 512) {
    int n = e >> 6, kk = e & 63;
    float v = b2f(RThi[kk * 136 + n]) + b2f(RTlo[kk * 136 + n]);
    wsp[WS_M1 + fragidx(n, kk, 2)] = f2b(v);
  }

  {
    s8v Shi[4], Slo[4];
#pragma unroll
    for (int ks = 0; ks < 4; ++ks) {
      int m = mr + c_;
      int k0 = ks * 32 + g_ * 8;
#pragma unroll
      for (int i = 0; i < 8; ++i) {
        Shi[ks][i] = RThi[(k0 + i) * 136 + m];
        Slo[ks][i] = RTlo[(k0 + i) * 136 + m];
      }
    }
    f4v acc[6];
#pragma unroll
    for (int nt = 0; nt < 6; ++nt) acc[nt] = (f4v){0.f, 0.f, 0.f, 0.f};
#pragma unroll
    for (int ks = 0; ks < 4; ++ks) {
#pragma unroll
      for (int nt = 0; nt < 6; ++nt) {
        s8v bh, bl;
#pragma unroll
        for (int i = 0; i < 8; ++i) {
          float v = sW2[(ks * 32 + g_ * 8 + i) * 96 + nt * 16 + c_];
          short h = f2b(v);
          bh[i] = h;
          bl[i] = f2b(v - b2f(h));
        }
        acc[nt] = MFMA(Shi[ks], bh, acc[nt]);
        acc[nt] = MFMA(Slo[ks], bh, acc[nt]);
        acc[nt] = MFMA(Shi[ks], bl, acc[nt]);
      }
    }
#pragma unroll
    for (int nt = 0; nt < 6; ++nt)
#pragma unroll
      for (int r = 0; r < 4; ++r)
        wsp[WS_W2K + fragidx(mr + g_ * 4 + r, nt * 16 + c_, 3)] = f2b(acc[nt][r]);
  }
}

// ---------------------------------------------------------------------------
// Kernel 2: SWAPPED-OPERAND fused pipeline. D = W·X^T: weights are A-operand
// (VGPR / frag-linear LDS), activations are B-operand read b128 from row-major
// [batch][feat] LDS tiles; C-fragments (4 contiguous feats @ fixed batch row)
// written as packed b64 — no transposes, no scatter writes anywhere.
// 256 thr = 4 waves (2 batch-groups x 2 feat-groups), 64-row tiles, 2 blk/CU.
// ---------------------------------------------------------------------------
__global__ __launch_bounds__(256, 2) void koop_main(
    const float* __restrict__ xg, const float* __restrict__ b1g,
    const float* __restrict__ bi1g, const float* __restrict__ bi2g,
    const short* __restrict__ wsp, float* __restrict__ outg) {
  extern __shared__ __align__(16) char smem[];
  short* sM1f = (short*)smem;          // 8192  frag-linear M1
  short* sI1f = sM1f + 8192;           // 12288 frag-linear I1
  short* sX   = sI1f + 12288;          // 64 x SX(72)  = 4608
  short* sH   = sX + 64 * SX;          // 64 x SH(104) = 6656   (H, then H2)
  short* sZ   = sH + 64 * SH;          // 64 x SZ(136) = 8704

  const int tid = threadIdx.x;
  const int lane = tid & 63, wid = tid >> 6;
  const int c_ = lane & 15, g_ = lane >> 4;
  const int bg = wid >> 1, fg = wid & 1;

  // ---- copy M1+I1 frag buffers to LDS (contiguous 40KB) ----
  for (int i = tid; i < 20480 / 8; i += 256)
    ((f4v*)sM1f)[i] = ((const f4v*)(wsp + WS_M1))[i];

  // ---- VGPR weights (A-frags) + bias frags (along feat axis) ----
  f4v wW1[3][2], wW2K[4][3], wI2[2][3];
  f4v bW1[3], bI1[3], bI2[2];
#pragma unroll
  for (int fb = 0; fb < 3; ++fb) {
    bW1[fb] = *(const f4v*)(b1g  + (fg * 3 + fb) * 16 + g_ * 4);  KEEP(bW1[fb]);
    bI1[fb] = *(const f4v*)(bi1g + (fg * 3 + fb) * 16 + g_ * 4);  KEEP(bI1[fb]);
#pragma unroll
    for (int ks = 0; ks < 2; ++ks) {
      wW1[fb][ks] = *(const f4v*)(wsp + WS_W1 + (((fg * 3 + fb) * 2 + ks) * 64 + lane) * 8);
      KEEP(wW1[fb][ks]);
    }
  }
#pragma unroll
  for (int fb = 0; fb < 4; ++fb)
#pragma unroll
    for (int ks = 0; ks < 3; ++ks) {
      wW2K[fb][ks] = *(const f4v*)(wsp + WS_W2K + (((fg * 4 + fb) * 3 + ks) * 64 + lane) * 8);
      KEEP(wW2K[fb][ks]);
    }
#pragma unroll
  for (int fb = 0; fb < 2; ++fb) {
    bI2[fb] = *(const f4v*)(bi2g + (fg * 2 + fb) * 16 + g_ * 4);  KEEP(bI2[fb]);
#pragma unroll
    for (int ks = 0; ks < 3; ++ks) {
      wI2[fb][ks] = *(const f4v*)(wsp + WS_I2 + (((fg * 2 + fb) * 3 + ks) * 64 + lane) * 8);
      KEEP(wI2[fb][ks]);
    }
  }

  // X staging map: thread -> (row, 16-float chunk)
  const int xr = tid >> 2, xq = tid & 3;

  // ---- prologue: stage X(tile0) ----
  int tile = blockIdx.x;
  {
    const float* src = xg + ((size_t)tile * 64 + xr) * 64 + xq * 16;
    *(s8v*)(sX + xr * SX + xq * 16) = pack8(*(const f4v*)src, *(const f4v*)(src + 4));
    *(s8v*)(sX + xr * SX + xq * 16 + 8) = pack8(*(const f4v*)(src + 8), *(const f4v*)(src + 12));
  }
  __syncthreads();

  for (; tile < NT64; tile += GRID) {
    const int nxt = tile + GRID;
    f4v pv0, pv1, pv2, pv3;
    if (nxt < NT64) {                         // issue next-tile loads (T14)
      const float* src = xg + ((size_t)nxt * 64 + xr) * 64 + xq * 16;
      pv0 = *(const f4v*)src;       pv1 = *(const f4v*)(src + 4);
      pv2 = *(const f4v*)(src + 8); pv3 = *(const f4v*)(src + 12);
    }

    // ---- stage 1: H^T-frags = W1 · X^T  (+b1, relu) ----
    s8v bx[2][2];
#pragma unroll
    for (int bb = 0; bb < 2; ++bb) {
      const int col0 = (bg * 2 + bb) * 16;
      bx[bb][0] = ldact(sX, col0, 0, SX);
      bx[bb][1] = ldact(sX, col0, 32, SX);
#pragma unroll
      for (int fb = 0; fb < 3; ++fb) {
        f4v acc = bW1[fb];
        acc = MFMA(__builtin_bit_cast(s8v, wW1[fb][0]), bx[bb][0], acc);
        acc = MFMA(__builtin_bit_cast(s8v, wW1[fb][1]), bx[bb][1], acc);
        *(s4v*)(sH + (col0 + c_) * SH + (fg * 3 + fb) * 16 + g_ * 4) = pack4r(acc);
      }
    }
    __syncthreads();  // b1: sH ready; sX reads done

    if (nxt < NT64) {                         // sX dead -> write X(t+1)
      *(s8v*)(sX + xr * SX + xq * 16) = pack8(pv0, pv1);
      *(s8v*)(sX + xr * SX + xq * 16 + 8) = pack8(pv2, pv3);
    }

    // ---- stage 2: Z = M1·X^T + W2K·H^T ----
    s8v m1f[4][2];
#pragma unroll
    for (int fb = 0; fb < 4; ++fb)
#pragma unroll
      for (int ks = 0; ks < 2; ++ks)
        m1f[fb][ks] = *(const s8v*)(sM1f + (((fg * 4 + fb) * 2 + ks) * 64 + lane) * 8);
#pragma unroll
    for (int bb = 0; bb < 2; ++bb) {
      const int col0 = (bg * 2 + bb) * 16;
      s8v hb0 = ldact(sH, col0, 0, SH);
      s8v hb1 = ldact(sH, col0, 32, SH);
      s8v hb2 = ldact(sH, col0, 64, SH);
#pragma unroll
      for (int fb = 0; fb < 4; ++fb) {
        f4v acc = (f4v){0.f, 0.f, 0.f, 0.f};
        acc = MFMA(m1f[fb][0], bx[bb][0], acc);
        acc = MFMA(m1f[fb][1], bx[bb][1], acc);
        acc = MFMA(__builtin_bit_cast(s8v, wW2K[fb][0]), hb0, acc);
        acc = MFMA(__builtin_bit_cast(s8v, wW2K[fb][1]), hb1, acc);
        acc = MFMA(__builtin_bit_cast(s8v, wW2K[fb][2]), hb2, acc);
        *(s4v*)(sZ + (col0 + c_) * SZ + (fg * 4 + fb) * 16 + g_ * 4) = pack4(acc);
      }
    }
    __syncthreads();  // b2: sZ ready; sH (H) dead

    // ---- stage 3: H2 = relu(I1·Z^T + bi1) -> sH region ----
    s8v i1f[3][4];
#pragma unroll
    for (int fb = 0; fb < 3; ++fb)
#pragma unroll
      for (int ks = 0; ks < 4; ++ks)
        i1f[fb][ks] = *(const s8v*)(sI1f + (((fg * 3 + fb) * 4 + ks) * 64 + lane) * 8);
#pragma unroll
    for (int bb = 0; bb < 2; ++bb) {
      const int col0 = (bg * 2 + bb) * 16;
      s8v zb[4];
#pragma unroll
      for (int ks = 0; ks < 4; ++ks) zb[ks] = ldact(sZ, col0, ks * 32, SZ);
#pragma unroll
      for (int fb = 0; fb < 3; ++fb) {
        f4v acc = bI1[fb];
#pragma unroll
        for (int ks = 0; ks < 4; ++ks) acc = MFMA(i1f[fb][ks], zb[ks], acc);
        *(s4v*)(sH + (col0 + c_) * SH + (fg * 3 + fb) * 16 + g_ * 4) = pack4r(acc);
      }
    }
    __syncthreads();  // b3: H2 ready

    // ---- stage 4: OUT = I2·H2^T + bi2 -> global (16B/lane stores) ----
#pragma unroll
    for (int bb = 0; bb < 2; ++bb) {
      const int col0 = (bg * 2 + bb) * 16;
      s8v h0 = ldact(sH, col0, 0, SH);
      s8v h1 = ldact(sH, col0, 32, SH);
      s8v h2 = ldact(sH, col0, 64, SH);
#pragma unroll
      for (int fb = 0; fb < 2; ++fb) {
        f4v acc = bI2[fb];
        acc = MFMA(__builtin_bit_cast(s8v, wI2[fb][0]), h0, acc);
        acc = MFMA(__builtin_bit_cast(s8v, wI2[fb][1]), h1, acc);
        acc = MFMA(__builtin_bit_cast(s8v, wI2[fb][2]), h2, acc);
        *(f4v*)(outg + ((size_t)tile * 64 + col0 + c_) * 64 + (fg * 2 + fb) * 16 + g_ * 4) = acc;
      }
    }
    __syncthreads();  // b4: H2 reads + X(t+1) writes complete
  }
}

#define PREP_LDS (128 * 136 * 2 * 2 + 128 * 96 * 4 + 130 * 4)   // 119304 B
#define MAIN_LDS ((8192 + 12288 + 64 * SX + 64 * SH + 64 * SZ) * 2)  // 80896 B

extern "C" void kernel_launch(void* const* d_in, const int* in_sizes, int n_in,
                              void* d_out, int out_size, void* d_ws, size_t ws_size,
                              hipStream_t stream) {
  (void)in_sizes; (void)n_in; (void)out_size; (void)ws_size;
  const float* t     = (const float*)d_in[0];
  const float* x     = (const float*)d_in[1];
  const float* A     = (const float*)d_in[2];
  const float* phiW1 = (const float*)d_in[3];
  const float* phib1 = (const float*)d_in[4];
  const float* phiW2 = (const float*)d_in[5];
  const float* invW1 = (const float*)d_in[6];
  const float* invb1 = (const float*)d_in[7];
  const float* invW2 = (const float*)d_in[8];
  const float* invb2 = (const float*)d_in[9];
  float* out = (float*)d_out;
  short* wsp = (short*)d_ws;

  (void)hipFuncSetAttribute((const void*)koop_prep,
                            hipFuncAttributeMaxDynamicSharedMemorySize, PREP_LDS);
  (void)hipFuncSetAttribute((const void*)koop_main,
                            hipFuncAttributeMaxDynamicSharedMemorySize, MAIN_LDS);

  koop_prep<<<1, 512, PREP_LDS, stream>>>(t, A, phiW2, phiW1, invW1, invW2, wsp);
  koop_main<<<GRID, 256, MAIN_LDS, stream>>>(x, phib1, invb1, invb2, wsp, out);
}